// Round 23
// baseline (441.912 us; speedup 1.0000x reference)
//
#include <hip/hip_runtime.h>
#include <math.h>

#define HH 1536
#define WW 1536
#define HWN (HH*WW)
#define CC 16
#define KSZ 5
#define PS 17
#define ISTR 128         // LDS column stride in elems (16 octets of 8) -> 256B
#define NMF 26           // 32x32x16 MFMAs per pair-tile: K = 17*24 = 408 -> 26 x K16
#define NQ 52            // A octet-groups: q = 2e + h1

typedef __bf16 bf16x8 __attribute__((ext_vector_type(8)));
typedef float f32x16 __attribute__((ext_vector_type(16)));

union Frag { uint4 u4; bf16x8 b8; };

__device__ inline unsigned short f32_to_bf16(float v) {
  unsigned int b = __float_as_uint(v);
  unsigned int r = (b + 0x7FFFu + ((b >> 16) & 1u)) >> 16;
  return (unsigned short)r;
}

__device__ inline float softplusf(float x) {
  return x > 20.f ? x : log1pf(expf(x));
}

__device__ inline float waveSum(float v) {
#pragma unroll
  for (int o = 32; o; o >>= 1) v += __shfl_xor(v, o);
  return v;
}

// ---------------- K1: fused content score + exp + (last block) global reduce ----------
// Last block computes S = sum(e), gate scalars, and the 5x5 shift-kernel softmax —
// the former k_mid1 kernel, fused via atomic-counter last-block pattern.
__global__ void k_scoreexp(const float* __restrict__ mem, const float* __restrict__ key,
                           const float* __restrict__ beta, const float* __restrict__ gate,
                           const float* __restrict__ shift, float* __restrict__ e,
                           float* __restrict__ red, float* __restrict__ scal,
                           float* __restrict__ skb, unsigned int* __restrict__ cnt) {
  __shared__ float sm[4];
  __shared__ bool isLast;
  __shared__ float rsm[256];
  float kv[CC];
  float kn = 0.f;
#pragma unroll
  for (int c = 0; c < CC; c++) { kv[c] = key[c]; kn += kv[c] * kv[c]; }
  float bp = softplusf(beta[0]);
  float scale = bp / fmaxf(sqrtf(kn), 1e-8f);

  int hw4 = (blockIdx.x * 256 + threadIdx.x) * 4;
  float d0 = 0.f, d1 = 0.f, d2 = 0.f, d3 = 0.f;
  float n0 = 0.f, n1 = 0.f, n2 = 0.f, n3 = 0.f;
#pragma unroll
  for (int c = 0; c < CC; c++) {
    float4 m = *reinterpret_cast<const float4*>(mem + (size_t)c * HWN + hw4);
    d0 += m.x * kv[c]; d1 += m.y * kv[c]; d2 += m.z * kv[c]; d3 += m.w * kv[c];
    n0 += m.x * m.x;   n1 += m.y * m.y;   n2 += m.z * m.z;   n3 += m.w * m.w;
  }
  float4 ev;
  ev.x = expf(scale * d0 / fmaxf(sqrtf(n0), 1e-8f) - bp);
  ev.y = expf(scale * d1 / fmaxf(sqrtf(n1), 1e-8f) - bp);
  ev.z = expf(scale * d2 / fmaxf(sqrtf(n2), 1e-8f) - bp);
  ev.w = expf(scale * d3 / fmaxf(sqrtf(n3), 1e-8f) - bp);
  *reinterpret_cast<float4*>(e + hw4) = ev;

  float lsum = waveSum(ev.x + ev.y + ev.z + ev.w);
  if ((threadIdx.x & 63) == 0) sm[threadIdx.x >> 6] = lsum;
  __syncthreads();
  if (threadIdx.x == 0) {
    red[blockIdx.x] = sm[0] + sm[1] + sm[2] + sm[3];
    __threadfence();
    unsigned int old = atomicAdd(cnt, 1u);
    isLast = (old == gridDim.x - 1);
  }
  __syncthreads();
  if (!isLast) return;
  __threadfence();   // acquire: see all blocks' red[] writes

  // ---- last block: reduce S, compute gate scalars + shift softmax (ex-k_mid1) ----
  float s = 0.f;
  for (int i = threadIdx.x; i < 2304; i += 256) s += red[i];
  rsm[threadIdx.x] = s;
  __syncthreads();
  for (int st = 128; st; st >>= 1) {
    if (threadIdx.x < st) rsm[threadIdx.x] += rsm[threadIdx.x + st];
    __syncthreads();
  }
  if (threadIdx.x == 0) {
    float S = rsm[0];
    float g = 1.f / (1.f + expf(-gate[0]));
    scal[3] = g / S;       // g * w_c = (g/S) * e
    scal[4] = 1.f - g;
    float mx = -INFINITY;
    for (int i = 0; i < KSZ * KSZ; i++) mx = fmaxf(mx, shift[i]);
    float ee[KSZ * KSZ];
    float sum = 0.f;
    for (int i = 0; i < KSZ * KSZ; i++) { ee[i] = expf(shift[i] - mx); sum += ee[i]; }
    for (int i = 0; i < KSZ * KSZ; i++) skb[i] = ee[i] / sum;
  }
}

// ---------------- K2: fused wg + 5x5 circular conv + pow(zeta) -> bf16 t
//                  + (last block) S2 reduce + A-fragment build (ex-k_mid2) ----------
__global__ void k_shiftf(const float* __restrict__ e, const float* __restrict__ prev,
                         const float* __restrict__ scal, const float* __restrict__ skb,
                         const float* __restrict__ sharpen, const float* __restrict__ patch,
                         unsigned short* __restrict__ tbf, float* __restrict__ red,
                         unsigned short* __restrict__ afrag, float* __restrict__ scal_out,
                         unsigned int* __restrict__ cnt) {
  __shared__ float tile[20][21];
  __shared__ float sks[KSZ * KSZ];
  __shared__ float sm[4];
  __shared__ bool isLast;
  __shared__ float rsm[256];
  int tx = threadIdx.x & 15, ty = threadIdx.x >> 4;
  int x0 = blockIdx.x * 16, y0 = blockIdx.y * 16;
  if (threadIdx.x < KSZ * KSZ) sks[threadIdx.x] = skb[threadIdx.x];
  float gS = scal[3], og = scal[4];
  for (int i = threadIdx.x; i < 400; i += 256) {
    int r = i / 20, c = i % 20;
    int gy = (y0 + r - 2 + HH) % HH;
    int gx = (x0 + c - 2 + WW) % WW;
    int idx = gy * WW + gx;
    tile[r][c] = gS * e[idx] + og * prev[idx];
  }
  __syncthreads();
  float zeta = softplusf(sharpen[0]) + 1.f;
  float acc = 0.f;
#pragma unroll
  for (int i = 0; i < KSZ; i++)
#pragma unroll
    for (int j = 0; j < KSZ; j++)
      acc += sks[i * KSZ + j] * tile[ty + i][tx + j];
  float tp = powf(fmaxf(acc, 1e-8f), zeta);
  tbf[(y0 + ty) * WW + x0 + tx] = f32_to_bf16(tp);
  float lsum = waveSum(tp);
  if ((threadIdx.x & 63) == 0) sm[threadIdx.x >> 6] = lsum;
  __syncthreads();
  if (threadIdx.x == 0) {
    red[blockIdx.y * 96 + blockIdx.x] = sm[0] + sm[1] + sm[2] + sm[3];
    __threadfence();
    unsigned int old = atomicAdd(cnt, 1u);
    isLast = (old == 9216u - 1u);
  }
  __syncthreads();
  if (!isLast) return;
  __threadfence();   // acquire: see all blocks' red[] writes

  // ---- last block: reduce S2; build A-fragments (patch / S2) — ex-k_mid2 ----
  float s = 0.f;
  for (int i = threadIdx.x; i < 9216; i += 256) s += red[i];
  rsm[threadIdx.x] = s;
  __syncthreads();
  for (int st = 128; st; st >>= 1) {
    if (threadIdx.x < st) rsm[threadIdx.x] += rsm[threadIdx.x + st];
    __syncthreads();
  }
  __shared__ float sInv;
  if (threadIdx.x == 0) { sInv = 1.f / fmaxf(rsm[0], 1e-6f); scal_out[2] = sInv; }
  __syncthreads();
  float invS = sInv;
  for (int idx = threadIdx.x; idx < NQ * 32 * 8; idx += 256) {
    int j = idx & 7;
    int m = (idx >> 3) & 31;
    int q = idx >> 8;
    int c = m & 15, p = m >> 4;
    int k = q * 8 + j;
    int vv = k / 24;
    int u2 = k % 24;
    int u = 17 - u2 + p;
    float val = 0.f;
    if (vv <= 16 && u >= 0 && u <= 16) val = patch[(c * PS + u) * PS + vv] * invS;
    afrag[idx] = f32_to_bf16(val);
  }
}

// ---------------- K3: 17x17 true conv via 32x32x16 MFMA + mem add (r17 form) -------
// 1D grid, 4608 blocks; XCD-colocating decode (r17, +5 µs): z-siblings share one L2.
// 512 threads, 8 waves; x0 = 32*bx; wave t owns pair-base b = 64by+2z+8t.
// LDS column-major ca[X][i], swizzle slot = (oct ^ (X&7)) & 15.
// B-frag (wave t, MFMA e, lane): h1 = lane>>5, q = 2e+h1, vv = q/3, rr = q%3,
//   X = (lane&31) + 16 - vv (clamped), octet oc = t + rr -> one b128.
// D: col = lane&31 = x-offset; row = (reg&3)+8*(reg>>2)+4*h1; c = row&15, p = row>>4.
// Epilogue: normal mem loads (phase-split), NT stores (r20 A/B: plain stores -9.5 µs).
__global__ void __launch_bounds__(512, 6) k_conv17w(
    const unsigned short* __restrict__ tbf, const unsigned short* __restrict__ afrag,
    const float* __restrict__ mem, float* __restrict__ out) {
  __shared__ __align__(16) unsigned short ca[48 * ISTR];
  int tid = threadIdx.x;

  // XCD-colocating decode
  int bid = blockIdx.x;
  int tile7 = bid & 7;
  int rest = bid >> 3;
  int z = rest & 3;
  int tile = tile7 + 8 * (rest >> 2);    // in [0, 1152)
  int bx = tile % 48;
  int by = tile / 48;

  int x0 = bx * 32;
  int y00 = by * 64 + z * 2;            // first pair-base (t=0, p=0)
  int yBase = y00 - 9;

  // stage 48 cols x 80 rows (octets 0..9), swizzled b128 writes
  bool interior = (x0 >= 8) && (x0 + 40 <= WW) && (yBase >= 0) && (yBase + 80 <= HH);
  if (interior) {
    for (int idx = tid; idx < 480; idx += 512) {
      int X = idx % 48, oct = idx / 48;
      const unsigned short* p = tbf + (size_t)(yBase + oct * 8) * WW + (x0 - 8 + X);
      unsigned short sv[8];
#pragma unroll
      for (int j = 0; j < 8; j++) sv[j] = p[(size_t)j * WW];
      uint4 qv;
      qv.x = (unsigned)sv[0] | ((unsigned)sv[1] << 16);
      qv.y = (unsigned)sv[2] | ((unsigned)sv[3] << 16);
      qv.z = (unsigned)sv[4] | ((unsigned)sv[5] << 16);
      qv.w = (unsigned)sv[6] | ((unsigned)sv[7] << 16);
      int slot = (oct ^ (X & 7)) & 15;
      *reinterpret_cast<uint4*>(reinterpret_cast<char*>(ca) + X * (ISTR * 2) + (slot << 4)) = qv;
    }
  } else {
    for (int idx = tid; idx < 480; idx += 512) {
      int X = idx % 48, oct = idx / 48;
      int x = x0 - 8 + X;
      bool xok = (x >= 0) && (x < WW);
      int yb = yBase + oct * 8;
      unsigned short sv[8];
#pragma unroll
      for (int j = 0; j < 8; j++) {
        int y = yb + j;
        sv[j] = (xok && y >= 0 && y < HH) ? tbf[(size_t)y * WW + x] : (unsigned short)0;
      }
      uint4 qv;
      qv.x = (unsigned)sv[0] | ((unsigned)sv[1] << 16);
      qv.y = (unsigned)sv[2] | ((unsigned)sv[3] << 16);
      qv.z = (unsigned)sv[4] | ((unsigned)sv[5] << 16);
      qv.w = (unsigned)sv[6] | ((unsigned)sv[7] << 16);
      int slot = (oct ^ (X & 7)) & 15;
      *reinterpret_cast<uint4*>(reinterpret_cast<char*>(ca) + X * (ISTR * 2) + (slot << 4)) = qv;
    }
  }
  __syncthreads();

  int lane = tid & 63;
  int t = tid >> 6;                 // wave id = pair-tile index, 0..7
  int col = lane & 31, h1 = lane >> 5;

  f32x16 acc;
#pragma unroll
  for (int i = 0; i < 16; i++) acc[i] = 0.f;

  const unsigned short* pa = afrag + ((size_t)h1 * 32 + col) * 8;  // + e*512 elems per iter
  const char* cab = reinterpret_cast<const char*>(ca);

#pragma unroll
  for (int e = 0; e < NMF; e++) {
    // q = 2e + h1; vv0/vv1, rr0/rr1 are compile-time constants
    const int q0 = 2 * e;
    const int vv0 = q0 / 3,       rr0 = q0 % 3;
    const int vv1 = (q0 + 1) / 3, rr1 = (q0 + 1) % 3;
    int vv = h1 ? vv1 : vv0;
    int rr = h1 ? rr1 : rr0;
    int X = col + 16 - vv;
    if (X < 0) X = 0;              // q=51 pad; A is zero there
    int slot = ((t + rr) ^ (X & 7)) & 15;
    Frag B;
    B.u4 = *reinterpret_cast<const uint4*>(cab + X * (ISTR * 2) + (slot << 4));
    Frag A;
    A.u4 = *reinterpret_cast<const uint4*>(pa + (size_t)e * 512);
    acc = __builtin_amdgcn_mfma_f32_32x32x16_bf16(A.b8, B.b8, acc, 0, 0, 0);
  }

  // epilogue: out[c][b+p][x0+col] = mem + acc (invS already folded into A)
  int xo = x0 + col;
  int b = y00 + 8 * t;
  unsigned int offs[16];
  float vals[16];
#pragma unroll
  for (int reg = 0; reg < 16; reg++) {
    int row = (reg & 3) + 8 * (reg >> 2) + 4 * h1;
    int c = row & 15;
    int p = row >> 4;
    offs[reg] = (unsigned int)(c * HWN + (b + p) * WW + xo);
    vals[reg] = mem[offs[reg]];
  }
#pragma unroll
  for (int reg = 0; reg < 16; reg++) {
    __builtin_nontemporal_store(vals[reg] + acc[reg], out + offs[reg]);
  }
}

// ---------------- host ----------------
extern "C" void kernel_launch(void* const* d_in, const int* in_sizes, int n_in,
                              void* d_out, int out_size, void* d_ws, size_t ws_size,
                              hipStream_t stream) {
  const float* key     = (const float*)d_in[0];
  const float* beta    = (const float*)d_in[1];
  const float* gate    = (const float*)d_in[2];
  const float* shift   = (const float*)d_in[3];
  const float* sharpen = (const float*)d_in[4];
  const float* prev    = (const float*)d_in[5];
  const float* patch   = (const float*)d_in[6];
  const float* mem     = (const float*)d_in[7];
  float* out = (float*)d_out;

  // ws layout: tbf ushort[HWN] | red f32[9216] | scal f32[16] | skb f32[32]
  //            | afrag ushort[13312] | cnt uint[4]
  float* ws = (float*)d_ws;
  unsigned short* tbf = (unsigned short*)ws;
  float* red  = ws + HWN / 2;
  float* scal = red + 9216;
  float* skb  = scal + 16;
  unsigned short* afrag = (unsigned short*)(skb + 32);
  unsigned int* cnt = (unsigned int*)(afrag + 13312);

  // e lives in d_out (dead before k_conv17w rewrites it)
  float* e = out;

  hipMemsetAsync(cnt, 0, 2 * sizeof(unsigned int), stream);
  k_scoreexp<<<2304, 256, 0, stream>>>(mem, key, beta, gate, shift, e, red, scal, skb, cnt);
  dim3 g2(96, 96);
  k_shiftf<<<g2, 256, 0, stream>>>(e, prev, scal, skb, sharpen, patch, tbf, red, afrag,
                                   scal, cnt + 1);
  k_conv17w<<<4608, 512, 0, stream>>>(tbf, afrag, mem, out);
}

// Round 24
// 241.668 us; speedup vs baseline: 1.8286x; 1.8286x over previous
//
#include <hip/hip_runtime.h>
#include <math.h>

#define HH 1536
#define WW 1536
#define HWN (HH*WW)
#define CC 16
#define KSZ 5
#define PS 17
#define ISTR 128         // LDS column stride in elems (16 octets of 8) -> 256B
#define NMF 26           // 32x32x16 MFMAs per pair-tile: K = 17*24 = 408 -> 26 x K16
#define NQ 52            // A octet-groups: q = 2e + h1

typedef __bf16 bf16x8 __attribute__((ext_vector_type(8)));
typedef float f32x16 __attribute__((ext_vector_type(16)));

union Frag { uint4 u4; bf16x8 b8; };

__device__ inline unsigned short f32_to_bf16(float v) {
  unsigned int b = __float_as_uint(v);
  unsigned int r = (b + 0x7FFFu + ((b >> 16) & 1u)) >> 16;
  return (unsigned short)r;
}

__device__ inline float softplusf(float x) {
  return x > 20.f ? x : log1pf(expf(x));
}

__device__ inline float waveSum(float v) {
#pragma unroll
  for (int o = 32; o; o >>= 1) v += __shfl_xor(v, o);
  return v;
}

// ---------------- K1: fused content score + exp + (last block) global reduce ----------
// Visibility via ATOMICS ONLY (r23 lesson: per-block __threadfence = per-block L2
// writeback on non-coherent XCD L2s = 283 µs stall). atomicExch publishes partials
// (coherent, parallel, deterministic); forced use of its return orders it before the
// arrival-counter atomicAdd; last block reads partials with atomicAdd(p, 0.f).
__global__ void k_scoreexp(const float* __restrict__ mem, const float* __restrict__ key,
                           const float* __restrict__ beta, const float* __restrict__ gate,
                           const float* __restrict__ shift, float* __restrict__ e,
                           float* __restrict__ red, float* __restrict__ scal,
                           float* __restrict__ skb, unsigned int* __restrict__ cnt) {
  __shared__ float sm[4];
  __shared__ bool isLast;
  __shared__ float rsm[256];
  float kv[CC];
  float kn = 0.f;
#pragma unroll
  for (int c = 0; c < CC; c++) { kv[c] = key[c]; kn += kv[c] * kv[c]; }
  float bp = softplusf(beta[0]);
  float scale = bp / fmaxf(sqrtf(kn), 1e-8f);

  int hw4 = (blockIdx.x * 256 + threadIdx.x) * 4;
  float d0 = 0.f, d1 = 0.f, d2 = 0.f, d3 = 0.f;
  float n0 = 0.f, n1 = 0.f, n2 = 0.f, n3 = 0.f;
#pragma unroll
  for (int c = 0; c < CC; c++) {
    float4 m = *reinterpret_cast<const float4*>(mem + (size_t)c * HWN + hw4);
    d0 += m.x * kv[c]; d1 += m.y * kv[c]; d2 += m.z * kv[c]; d3 += m.w * kv[c];
    n0 += m.x * m.x;   n1 += m.y * m.y;   n2 += m.z * m.z;   n3 += m.w * m.w;
  }
  float4 ev;
  ev.x = expf(scale * d0 / fmaxf(sqrtf(n0), 1e-8f) - bp);
  ev.y = expf(scale * d1 / fmaxf(sqrtf(n1), 1e-8f) - bp);
  ev.z = expf(scale * d2 / fmaxf(sqrtf(n2), 1e-8f) - bp);
  ev.w = expf(scale * d3 / fmaxf(sqrtf(n3), 1e-8f) - bp);
  *reinterpret_cast<float4*>(e + hw4) = ev;

  float lsum = waveSum(ev.x + ev.y + ev.z + ev.w);
  if ((threadIdx.x & 63) == 0) sm[threadIdx.x >> 6] = lsum;
  __syncthreads();
  if (threadIdx.x == 0) {
    float part = sm[0] + sm[1] + sm[2] + sm[3];
    float old = atomicExch(&red[blockIdx.x], part);   // coherent publish
    __asm__ volatile("" :: "v"(old));                 // force completion before counter
    unsigned int o = atomicAdd(cnt, 1u);
    isLast = (o == gridDim.x - 1);
  }
  __syncthreads();
  if (!isLast) return;

  // ---- last block: reduce S (coherent atomic reads), gate scalars + shift softmax ----
  float s = 0.f;
  for (int i = threadIdx.x; i < 2304; i += 256) s += atomicAdd(&red[i], 0.f);
  rsm[threadIdx.x] = s;
  __syncthreads();
  for (int st = 128; st; st >>= 1) {
    if (threadIdx.x < st) rsm[threadIdx.x] += rsm[threadIdx.x + st];
    __syncthreads();
  }
  if (threadIdx.x == 0) {
    float S = rsm[0];
    float g = 1.f / (1.f + expf(-gate[0]));
    scal[3] = g / S;       // g * w_c = (g/S) * e
    scal[4] = 1.f - g;
    float mx = -INFINITY;
    for (int i = 0; i < KSZ * KSZ; i++) mx = fmaxf(mx, shift[i]);
    float ee[KSZ * KSZ];
    float sum = 0.f;
    for (int i = 0; i < KSZ * KSZ; i++) { ee[i] = expf(shift[i] - mx); sum += ee[i]; }
    for (int i = 0; i < KSZ * KSZ; i++) skb[i] = ee[i] / sum;
  }
}

// ---------------- K2: fused wg + 5x5 circular conv + pow(zeta) -> bf16 t
//                  + (last block) S2 reduce + A-fragment build — atomics only ---------
__global__ void k_shiftf(const float* __restrict__ e, const float* __restrict__ prev,
                         const float* __restrict__ scal, const float* __restrict__ skb,
                         const float* __restrict__ sharpen, const float* __restrict__ patch,
                         unsigned short* __restrict__ tbf, float* __restrict__ red,
                         unsigned short* __restrict__ afrag, float* __restrict__ scal_out,
                         unsigned int* __restrict__ cnt) {
  __shared__ float tile[20][21];
  __shared__ float sks[KSZ * KSZ];
  __shared__ float sm[4];
  __shared__ bool isLast;
  __shared__ float rsm[256];
  int tx = threadIdx.x & 15, ty = threadIdx.x >> 4;
  int x0 = blockIdx.x * 16, y0 = blockIdx.y * 16;
  if (threadIdx.x < KSZ * KSZ) sks[threadIdx.x] = skb[threadIdx.x];
  float gS = scal[3], og = scal[4];
  for (int i = threadIdx.x; i < 400; i += 256) {
    int r = i / 20, c = i % 20;
    int gy = (y0 + r - 2 + HH) % HH;
    int gx = (x0 + c - 2 + WW) % WW;
    int idx = gy * WW + gx;
    tile[r][c] = gS * e[idx] + og * prev[idx];
  }
  __syncthreads();
  float zeta = softplusf(sharpen[0]) + 1.f;
  float acc = 0.f;
#pragma unroll
  for (int i = 0; i < KSZ; i++)
#pragma unroll
    for (int j = 0; j < KSZ; j++)
      acc += sks[i * KSZ + j] * tile[ty + i][tx + j];
  float tp = powf(fmaxf(acc, 1e-8f), zeta);
  tbf[(y0 + ty) * WW + x0 + tx] = f32_to_bf16(tp);
  float lsum = waveSum(tp);
  if ((threadIdx.x & 63) == 0) sm[threadIdx.x >> 6] = lsum;
  __syncthreads();
  if (threadIdx.x == 0) {
    float part = sm[0] + sm[1] + sm[2] + sm[3];
    float old = atomicExch(&red[blockIdx.y * 96 + blockIdx.x], part);
    __asm__ volatile("" :: "v"(old));
    unsigned int o = atomicAdd(cnt, 1u);
    isLast = (o == 9216u - 1u);
  }
  __syncthreads();
  if (!isLast) return;

  // ---- last block: reduce S2 (coherent atomic reads); build A-fragments ----
  float s = 0.f;
  for (int i = threadIdx.x; i < 9216; i += 256) s += atomicAdd(&red[i], 0.f);
  rsm[threadIdx.x] = s;
  __syncthreads();
  for (int st = 128; st; st >>= 1) {
    if (threadIdx.x < st) rsm[threadIdx.x] += rsm[threadIdx.x + st];
    __syncthreads();
  }
  __shared__ float sInv;
  if (threadIdx.x == 0) { sInv = 1.f / fmaxf(rsm[0], 1e-6f); scal_out[2] = sInv; }
  __syncthreads();
  float invS = sInv;
  for (int idx = threadIdx.x; idx < NQ * 32 * 8; idx += 256) {
    int j = idx & 7;
    int m = (idx >> 3) & 31;
    int q = idx >> 8;
    int c = m & 15, p = m >> 4;
    int k = q * 8 + j;
    int vv = k / 24;
    int u2 = k % 24;
    int u = 17 - u2 + p;
    float val = 0.f;
    if (vv <= 16 && u >= 0 && u <= 16) val = patch[(c * PS + u) * PS + vv] * invS;
    afrag[idx] = f32_to_bf16(val);
  }
}

// ---------------- K3: 17x17 true conv via 32x32x16 MFMA + mem add (r17 form) -------
// 1D grid, 4608 blocks; XCD-colocating decode (r17, +5 µs): z-siblings share one L2.
// 512 threads, 8 waves; x0 = 32*bx; wave t owns pair-base b = 64by+2z+8t.
// LDS column-major ca[X][i], swizzle slot = (oct ^ (X&7)) & 15.
// B-frag (wave t, MFMA e, lane): h1 = lane>>5, q = 2e+h1, vv = q/3, rr = q%3,
//   X = (lane&31) + 16 - vv (clamped), octet oc = t + rr -> one b128.
// D: col = lane&31 = x-offset; row = (reg&3)+8*(reg>>2)+4*h1; c = row&15, p = row>>4.
// Epilogue: normal mem loads (phase-split), NT stores (r20 A/B: plain stores -9.5 µs).
__global__ void __launch_bounds__(512, 6) k_conv17w(
    const unsigned short* __restrict__ tbf, const unsigned short* __restrict__ afrag,
    const float* __restrict__ mem, float* __restrict__ out) {
  __shared__ __align__(16) unsigned short ca[48 * ISTR];
  int tid = threadIdx.x;

  // XCD-colocating decode
  int bid = blockIdx.x;
  int tile7 = bid & 7;
  int rest = bid >> 3;
  int z = rest & 3;
  int tile = tile7 + 8 * (rest >> 2);    // in [0, 1152)
  int bx = tile % 48;
  int by = tile / 48;

  int x0 = bx * 32;
  int y00 = by * 64 + z * 2;            // first pair-base (t=0, p=0)
  int yBase = y00 - 9;

  // stage 48 cols x 80 rows (octets 0..9), swizzled b128 writes
  bool interior = (x0 >= 8) && (x0 + 40 <= WW) && (yBase >= 0) && (yBase + 80 <= HH);
  if (interior) {
    for (int idx = tid; idx < 480; idx += 512) {
      int X = idx % 48, oct = idx / 48;
      const unsigned short* p = tbf + (size_t)(yBase + oct * 8) * WW + (x0 - 8 + X);
      unsigned short sv[8];
#pragma unroll
      for (int j = 0; j < 8; j++) sv[j] = p[(size_t)j * WW];
      uint4 qv;
      qv.x = (unsigned)sv[0] | ((unsigned)sv[1] << 16);
      qv.y = (unsigned)sv[2] | ((unsigned)sv[3] << 16);
      qv.z = (unsigned)sv[4] | ((unsigned)sv[5] << 16);
      qv.w = (unsigned)sv[6] | ((unsigned)sv[7] << 16);
      int slot = (oct ^ (X & 7)) & 15;
      *reinterpret_cast<uint4*>(reinterpret_cast<char*>(ca) + X * (ISTR * 2) + (slot << 4)) = qv;
    }
  } else {
    for (int idx = tid; idx < 480; idx += 512) {
      int X = idx % 48, oct = idx / 48;
      int x = x0 - 8 + X;
      bool xok = (x >= 0) && (x < WW);
      int yb = yBase + oct * 8;
      unsigned short sv[8];
#pragma unroll
      for (int j = 0; j < 8; j++) {
        int y = yb + j;
        sv[j] = (xok && y >= 0 && y < HH) ? tbf[(size_t)y * WW + x] : (unsigned short)0;
      }
      uint4 qv;
      qv.x = (unsigned)sv[0] | ((unsigned)sv[1] << 16);
      qv.y = (unsigned)sv[2] | ((unsigned)sv[3] << 16);
      qv.z = (unsigned)sv[4] | ((unsigned)sv[5] << 16);
      qv.w = (unsigned)sv[6] | ((unsigned)sv[7] << 16);
      int slot = (oct ^ (X & 7)) & 15;
      *reinterpret_cast<uint4*>(reinterpret_cast<char*>(ca) + X * (ISTR * 2) + (slot << 4)) = qv;
    }
  }
  __syncthreads();

  int lane = tid & 63;
  int t = tid >> 6;                 // wave id = pair-tile index, 0..7
  int col = lane & 31, h1 = lane >> 5;

  f32x16 acc;
#pragma unroll
  for (int i = 0; i < 16; i++) acc[i] = 0.f;

  const unsigned short* pa = afrag + ((size_t)h1 * 32 + col) * 8;  // + e*512 elems per iter
  const char* cab = reinterpret_cast<const char*>(ca);

#pragma unroll
  for (int e = 0; e < NMF; e++) {
    // q = 2e + h1; vv0/vv1, rr0/rr1 are compile-time constants
    const int q0 = 2 * e;
    const int vv0 = q0 / 3,       rr0 = q0 % 3;
    const int vv1 = (q0 + 1) / 3, rr1 = (q0 + 1) % 3;
    int vv = h1 ? vv1 : vv0;
    int rr = h1 ? rr1 : rr0;
    int X = col + 16 - vv;
    if (X < 0) X = 0;              // q=51 pad; A is zero there
    int slot = ((t + rr) ^ (X & 7)) & 15;
    Frag B;
    B.u4 = *reinterpret_cast<const uint4*>(cab + X * (ISTR * 2) + (slot << 4));
    Frag A;
    A.u4 = *reinterpret_cast<const uint4*>(pa + (size_t)e * 512);
    acc = __builtin_amdgcn_mfma_f32_32x32x16_bf16(A.b8, B.b8, acc, 0, 0, 0);
  }

  // epilogue: out[c][b+p][x0+col] = mem + acc (invS already folded into A)
  int xo = x0 + col;
  int b = y00 + 8 * t;
  unsigned int offs[16];
  float vals[16];
#pragma unroll
  for (int reg = 0; reg < 16; reg++) {
    int row = (reg & 3) + 8 * (reg >> 2) + 4 * h1;
    int c = row & 15;
    int p = row >> 4;
    offs[reg] = (unsigned int)(c * HWN + (b + p) * WW + xo);
    vals[reg] = mem[offs[reg]];
  }
#pragma unroll
  for (int reg = 0; reg < 16; reg++) {
    __builtin_nontemporal_store(vals[reg] + acc[reg], out + offs[reg]);
  }
}

// ---------------- host ----------------
extern "C" void kernel_launch(void* const* d_in, const int* in_sizes, int n_in,
                              void* d_out, int out_size, void* d_ws, size_t ws_size,
                              hipStream_t stream) {
  const float* key     = (const float*)d_in[0];
  const float* beta    = (const float*)d_in[1];
  const float* gate    = (const float*)d_in[2];
  const float* shift   = (const float*)d_in[3];
  const float* sharpen = (const float*)d_in[4];
  const float* prev    = (const float*)d_in[5];
  const float* patch   = (const float*)d_in[6];
  const float* mem     = (const float*)d_in[7];
  float* out = (float*)d_out;

  // ws layout: tbf ushort[HWN] | red f32[9216] | scal f32[16] | skb f32[32]
  //            | afrag ushort[13312] | cnt uint[4]
  float* ws = (float*)d_ws;
  unsigned short* tbf = (unsigned short*)ws;
  float* red  = ws + HWN / 2;
  float* scal = red + 9216;
  float* skb  = scal + 16;
  unsigned short* afrag = (unsigned short*)(skb + 32);
  unsigned int* cnt = (unsigned int*)(afrag + 13312);

  // e lives in d_out (dead before k_conv17w rewrites it)
  float* e = out;

  hipMemsetAsync(cnt, 0, 2 * sizeof(unsigned int), stream);
  k_scoreexp<<<2304, 256, 0, stream>>>(mem, key, beta, gate, shift, e, red, scal, skb, cnt);
  dim3 g2(96, 96);
  k_shiftf<<<g2, 256, 0, stream>>>(e, prev, scal, skb, sharpen, patch, tbf, red, afrag,
                                   scal, cnt + 1);
  k_conv17w<<<4608, 512, 0, stream>>>(tbf, afrag, mem, out);
}

// Round 25
// 141.382 us; speedup vs baseline: 3.1257x; 1.7093x over previous
//
#include <hip/hip_runtime.h>
#include <math.h>

#define HH 1536
#define WW 1536
#define HWN (HH*WW)
#define CC 16
#define KSZ 5
#define PS 17
#define ISTR 128         // LDS column stride in elems (16 octets of 8) -> 256B
#define NMF 26           // 32x32x16 MFMAs per pair-tile: K = 17*24 = 408 -> 26 x K16
#define NQ 52            // A octet-groups: q = 2e + h1

typedef __bf16 bf16x8 __attribute__((ext_vector_type(8)));
typedef float f32x16 __attribute__((ext_vector_type(16)));

union Frag { uint4 u4; bf16x8 b8; };

__device__ inline unsigned short f32_to_bf16(float v) {
  unsigned int b = __float_as_uint(v);
  unsigned int r = (b + 0x7FFFu + ((b >> 16) & 1u)) >> 16;
  return (unsigned short)r;
}

__device__ inline float softplusf(float x) {
  return x > 20.f ? x : log1pf(expf(x));
}

__device__ inline float waveSum(float v) {
#pragma unroll
  for (int o = 32; o; o >>= 1) v += __shfl_xor(v, o);
  return v;
}

// ---------------- K1: fused content score + exp (M = beta_pos bound) ----------------
__global__ void k_scoreexp(const float* __restrict__ mem, const float* __restrict__ key,
                           const float* __restrict__ beta, float* __restrict__ e,
                           float* __restrict__ red) {
  __shared__ float sm[4];
  float kv[CC];
  float kn = 0.f;
#pragma unroll
  for (int c = 0; c < CC; c++) { kv[c] = key[c]; kn += kv[c] * kv[c]; }
  float bp = softplusf(beta[0]);
  float scale = bp / fmaxf(sqrtf(kn), 1e-8f);

  int hw4 = (blockIdx.x * 256 + threadIdx.x) * 4;
  float d0 = 0.f, d1 = 0.f, d2 = 0.f, d3 = 0.f;
  float n0 = 0.f, n1 = 0.f, n2 = 0.f, n3 = 0.f;
#pragma unroll
  for (int c = 0; c < CC; c++) {
    float4 m = *reinterpret_cast<const float4*>(mem + (size_t)c * HWN + hw4);
    d0 += m.x * kv[c]; d1 += m.y * kv[c]; d2 += m.z * kv[c]; d3 += m.w * kv[c];
    n0 += m.x * m.x;   n1 += m.y * m.y;   n2 += m.z * m.z;   n3 += m.w * m.w;
  }
  float4 ev;
  ev.x = expf(scale * d0 / fmaxf(sqrtf(n0), 1e-8f) - bp);
  ev.y = expf(scale * d1 / fmaxf(sqrtf(n1), 1e-8f) - bp);
  ev.z = expf(scale * d2 / fmaxf(sqrtf(n2), 1e-8f) - bp);
  ev.w = expf(scale * d3 / fmaxf(sqrtf(n3), 1e-8f) - bp);
  *reinterpret_cast<float4*>(e + hw4) = ev;

  float lsum = waveSum(ev.x + ev.y + ev.z + ev.w);
  if ((threadIdx.x & 63) == 0) sm[threadIdx.x >> 6] = lsum;
  __syncthreads();
  if (threadIdx.x == 0) red[blockIdx.x] = sm[0] + sm[1] + sm[2] + sm[3];
}

// ---------------- K2: reduce S = sum(e); gate scalars; shift-kernel softmax ----------------
__global__ void k_mid1(const float* __restrict__ red, float* __restrict__ scal,
                       const float* __restrict__ shift, float* __restrict__ skb,
                       const float* __restrict__ gate) {
  __shared__ float sm[256];
  float s = 0.f;
  for (int i = threadIdx.x; i < 2304; i += 256) s += red[i];
  sm[threadIdx.x] = s;
  __syncthreads();
  for (int st = 128; st; st >>= 1) {
    if (threadIdx.x < st) sm[threadIdx.x] += sm[threadIdx.x + st];
    __syncthreads();
  }
  if (threadIdx.x == 0) {
    float S = sm[0];
    float g = 1.f / (1.f + expf(-gate[0]));
    scal[3] = g / S;       // g * w_c = (g/S) * e
    scal[4] = 1.f - g;
    float mx = -INFINITY;
    for (int i = 0; i < KSZ * KSZ; i++) mx = fmaxf(mx, shift[i]);
    float ee[KSZ * KSZ];
    float sum = 0.f;
    for (int i = 0; i < KSZ * KSZ; i++) { ee[i] = expf(shift[i] - mx); sum += ee[i]; }
    for (int i = 0; i < KSZ * KSZ; i++) skb[i] = ee[i] / sum;
  }
}

// ---------------- K3: fused wg + 5x5 circular conv + pow(zeta) -> bf16 t, partial sums ----
__global__ void k_shiftf(const float* __restrict__ e, const float* __restrict__ prev,
                         const float* __restrict__ scal, const float* __restrict__ skb,
                         const float* __restrict__ sharpen, unsigned short* __restrict__ tbf,
                         float* __restrict__ red) {
  __shared__ float tile[20][21];
  __shared__ float sks[KSZ * KSZ];
  __shared__ float sm[4];
  int tx = threadIdx.x & 15, ty = threadIdx.x >> 4;
  int x0 = blockIdx.x * 16, y0 = blockIdx.y * 16;
  if (threadIdx.x < KSZ * KSZ) sks[threadIdx.x] = skb[threadIdx.x];
  float gS = scal[3], og = scal[4];
  for (int i = threadIdx.x; i < 400; i += 256) {
    int r = i / 20, c = i % 20;
    int gy = (y0 + r - 2 + HH) % HH;
    int gx = (x0 + c - 2 + WW) % WW;
    int idx = gy * WW + gx;
    tile[r][c] = gS * e[idx] + og * prev[idx];
  }
  __syncthreads();
  float zeta = softplusf(sharpen[0]) + 1.f;
  float acc = 0.f;
#pragma unroll
  for (int i = 0; i < KSZ; i++)
#pragma unroll
    for (int j = 0; j < KSZ; j++)
      acc += sks[i * KSZ + j] * tile[ty + i][tx + j];
  float tp = powf(fmaxf(acc, 1e-8f), zeta);
  tbf[(y0 + ty) * WW + x0 + tx] = f32_to_bf16(tp);
  float lsum = waveSum(tp);
  if ((threadIdx.x & 63) == 0) sm[threadIdx.x >> 6] = lsum;
  __syncthreads();
  if (threadIdx.x == 0) red[blockIdx.y * 96 + blockIdx.x] = sm[0] + sm[1] + sm[2] + sm[3];
}

// ---------------- K4: reduce S2; build A-fragments (patch / S2) for 32x32x16 ----------
// afrag[(q*32 + m)*8 + j], q in [0,52), m = (c | p<<4) in [0,32), j in [0,8).
// k = 8q + j ; vv = k / 24 ; u2 = k % 24 ; u = 17 - u2 + p.
// value = patch[c][u][vv]*invS if (vv<=16 && 0<=u<=16) else 0.
__global__ void k_mid2(const float* __restrict__ red, float* __restrict__ scal,
                       const float* __restrict__ patch, unsigned short* __restrict__ afrag) {
  __shared__ float sm[256];
  __shared__ float sInv;
  float s = 0.f;
  for (int i = threadIdx.x; i < 9216; i += 256) s += red[i];
  sm[threadIdx.x] = s;
  __syncthreads();
  for (int st = 128; st; st >>= 1) {
    if (threadIdx.x < st) sm[threadIdx.x] += sm[threadIdx.x + st];
    __syncthreads();
  }
  if (threadIdx.x == 0) { sInv = 1.f / fmaxf(sm[0], 1e-6f); scal[2] = sInv; }
  __syncthreads();
  float invS = sInv;
  for (int idx = threadIdx.x; idx < NQ * 32 * 8; idx += 256) {
    int j = idx & 7;
    int m = (idx >> 3) & 31;
    int q = idx >> 8;
    int c = m & 15, p = m >> 4;
    int k = q * 8 + j;
    int vv = k / 24;
    int u2 = k % 24;
    int u = 17 - u2 + p;
    float val = 0.f;
    if (vv <= 16 && u >= 0 && u <= 16) val = patch[(c * PS + u) * PS + vv] * invS;
    afrag[idx] = f32_to_bf16(val);
  }
}

// ---------------- K5: 17x17 true conv via 32x32x16 MFMA + mem add ----------------
// 1D grid, 4608 blocks; XCD-colocating decode (r17, +5 µs): z-siblings share one L2.
// 512 threads, 8 waves; x0 = 32*bx; wave t owns pair-base b = 64by+2z+8t.
// LDS column-major ca[X][i], swizzle slot = (oct ^ (X&7)) & 15.
// B-frag (wave t, MFMA e, lane): h1 = lane>>5, q = 2e+h1, vv = q/3, rr = q%3,
//   X = (lane&31) + 16 - vv (clamped), octet oc = t + rr -> one b128.
// D: col = lane&31 = x-offset; row = (reg&3)+8*(reg>>2)+4*h1; c = row&15, p = row>>4.
// Epilogue: normal mem loads (phase-split), NT stores (r20 A/B: plain stores -9.5 µs).
__global__ void __launch_bounds__(512, 6) k_conv17w(
    const unsigned short* __restrict__ tbf, const unsigned short* __restrict__ afrag,
    const float* __restrict__ mem, float* __restrict__ out) {
  __shared__ __align__(16) unsigned short ca[48 * ISTR];
  int tid = threadIdx.x;

  // XCD-colocating decode
  int bid = blockIdx.x;
  int tile7 = bid & 7;
  int rest = bid >> 3;
  int z = rest & 3;
  int tile = tile7 + 8 * (rest >> 2);    // in [0, 1152)
  int bx = tile % 48;
  int by = tile / 48;

  int x0 = bx * 32;
  int y00 = by * 64 + z * 2;            // first pair-base (t=0, p=0)
  int yBase = y00 - 9;

  // stage 48 cols x 80 rows (octets 0..9), swizzled b128 writes
  bool interior = (x0 >= 8) && (x0 + 40 <= WW) && (yBase >= 0) && (yBase + 80 <= HH);
  if (interior) {
    for (int idx = tid; idx < 480; idx += 512) {
      int X = idx % 48, oct = idx / 48;
      const unsigned short* p = tbf + (size_t)(yBase + oct * 8) * WW + (x0 - 8 + X);
      unsigned short sv[8];
#pragma unroll
      for (int j = 0; j < 8; j++) sv[j] = p[(size_t)j * WW];
      uint4 qv;
      qv.x = (unsigned)sv[0] | ((unsigned)sv[1] << 16);
      qv.y = (unsigned)sv[2] | ((unsigned)sv[3] << 16);
      qv.z = (unsigned)sv[4] | ((unsigned)sv[5] << 16);
      qv.w = (unsigned)sv[6] | ((unsigned)sv[7] << 16);
      int slot = (oct ^ (X & 7)) & 15;
      *reinterpret_cast<uint4*>(reinterpret_cast<char*>(ca) + X * (ISTR * 2) + (slot << 4)) = qv;
    }
  } else {
    for (int idx = tid; idx < 480; idx += 512) {
      int X = idx % 48, oct = idx / 48;
      int x = x0 - 8 + X;
      bool xok = (x >= 0) && (x < WW);
      int yb = yBase + oct * 8;
      unsigned short sv[8];
#pragma unroll
      for (int j = 0; j < 8; j++) {
        int y = yb + j;
        sv[j] = (xok && y >= 0 && y < HH) ? tbf[(size_t)y * WW + x] : (unsigned short)0;
      }
      uint4 qv;
      qv.x = (unsigned)sv[0] | ((unsigned)sv[1] << 16);
      qv.y = (unsigned)sv[2] | ((unsigned)sv[3] << 16);
      qv.z = (unsigned)sv[4] | ((unsigned)sv[5] << 16);
      qv.w = (unsigned)sv[6] | ((unsigned)sv[7] << 16);
      int slot = (oct ^ (X & 7)) & 15;
      *reinterpret_cast<uint4*>(reinterpret_cast<char*>(ca) + X * (ISTR * 2) + (slot << 4)) = qv;
    }
  }
  __syncthreads();

  int lane = tid & 63;
  int t = tid >> 6;                 // wave id = pair-tile index, 0..7
  int col = lane & 31, h1 = lane >> 5;

  f32x16 acc;
#pragma unroll
  for (int i = 0; i < 16; i++) acc[i] = 0.f;

  const unsigned short* pa = afrag + ((size_t)h1 * 32 + col) * 8;  // + e*512 elems per iter
  const char* cab = reinterpret_cast<const char*>(ca);

#pragma unroll
  for (int e = 0; e < NMF; e++) {
    // q = 2e + h1; vv0/vv1, rr0/rr1 are compile-time constants
    const int q0 = 2 * e;
    const int vv0 = q0 / 3,       rr0 = q0 % 3;
    const int vv1 = (q0 + 1) / 3, rr1 = (q0 + 1) % 3;
    int vv = h1 ? vv1 : vv0;
    int rr = h1 ? rr1 : rr0;
    int X = col + 16 - vv;
    if (X < 0) X = 0;              // q=51 pad; A is zero there
    int slot = ((t + rr) ^ (X & 7)) & 15;
    Frag B;
    B.u4 = *reinterpret_cast<const uint4*>(cab + X * (ISTR * 2) + (slot << 4));
    Frag A;
    A.u4 = *reinterpret_cast<const uint4*>(pa + (size_t)e * 512);
    acc = __builtin_amdgcn_mfma_f32_32x32x16_bf16(A.b8, B.b8, acc, 0, 0, 0);
  }

  // epilogue: out[c][b+p][x0+col] = mem + acc (invS already folded into A)
  int xo = x0 + col;
  int b = y00 + 8 * t;
  unsigned int offs[16];
  float vals[16];
#pragma unroll
  for (int reg = 0; reg < 16; reg++) {
    int row = (reg & 3) + 8 * (reg >> 2) + 4 * h1;
    int c = row & 15;
    int p = row >> 4;
    offs[reg] = (unsigned int)(c * HWN + (b + p) * WW + xo);
    vals[reg] = mem[offs[reg]];
  }
#pragma unroll
  for (int reg = 0; reg < 16; reg++) {
    __builtin_nontemporal_store(vals[reg] + acc[reg], out + offs[reg]);
  }
}

// ---------------- host ----------------
extern "C" void kernel_launch(void* const* d_in, const int* in_sizes, int n_in,
                              void* d_out, int out_size, void* d_ws, size_t ws_size,
                              hipStream_t stream) {
  const float* key     = (const float*)d_in[0];
  const float* beta    = (const float*)d_in[1];
  const float* gate    = (const float*)d_in[2];
  const float* shift   = (const float*)d_in[3];
  const float* sharpen = (const float*)d_in[4];
  const float* prev    = (const float*)d_in[5];
  const float* patch   = (const float*)d_in[6];
  const float* mem     = (const float*)d_in[7];
  float* out = (float*)d_out;

  // ws layout: tbf ushort[HWN] | red f32[9216] | scal f32[16] | skb f32[32] | afrag ushort[13312]
  float* ws = (float*)d_ws;
  unsigned short* tbf = (unsigned short*)ws;
  float* red  = ws + HWN / 2;
  float* scal = red + 9216;
  float* skb  = scal + 16;
  unsigned short* afrag = (unsigned short*)(skb + 32);

  // e lives in d_out (dead before k_conv17w rewrites it)
  float* e = out;

  k_scoreexp<<<2304, 256, 0, stream>>>(mem, key, beta, e, red);
  k_mid1<<<1, 256, 0, stream>>>(red, scal, shift, skb, gate);
  dim3 g2(96, 96);
  k_shiftf<<<g2, 256, 0, stream>>>(e, prev, scal, skb, sharpen, tbf, red);
  k_mid2<<<1, 256, 0, stream>>>(red, scal, patch, afrag);
  k_conv17w<<<4608, 512, 0, stream>>>(tbf, afrag, mem, out);
}